// Round 12
// baseline (688.517 us; speedup 1.0000x reference)
//
#include <hip/hip_runtime.h>
#include <hip/hip_bf16.h>
#include <hip/hip_fp8.h>
#include <stdint.h>

// Problem constants (fixed by setup_inputs)
#define NN 16384
#define DD 512
#define BM 128
#define BN 256        // block tile 128x256
#define NCT2 64       // 256-wide column tiles (= NN/BN)
#define KT 4          // per-tile top-k kept (global top-10 from 64x top-4)
#define PPW 260       // epilogue pair-view pitch in DWORDS ([64 rowpairs][260])
#define NEG_INF (-3.0e38f)

// R19: pipeline compaction (verified GEMM math untouched). ~100 us of the
// 569 was serialization: 8 launches, sequential rank||scan (independent,
// complementary pipes), latency-bound p_kernel. (a) fused_post: one grid,
// first NR*128 blocks = rank, rest = scan @512thr/8rows -> overlap.
// (b) fused_pre: casts + diag (diag now dots fp32 inputs directly).
// (c) p_kernel 8 parts/entity (24 serial loads, was 48). (d) K-loop STAGE
// moved above MFMA cluster (buffer (t+2)%3 last read in compute t-1; all
// waves passed top-of-t barrier after that -> safe; vmcnt unchanged).

typedef unsigned short u16;
typedef _Float16 f16;
typedef __attribute__((ext_vector_type(8))) __bf16 bf16x8;   // MFMA A/B operand
typedef __attribute__((ext_vector_type(8))) short sh8;       // 16B vector
typedef __attribute__((ext_vector_type(8))) _Float16 f16x8;  // 16B of fp16
typedef __attribute__((ext_vector_type(4))) float f32x4;     // MFMA C/D

__device__ __forceinline__ u16 f2bf(float f) {  // RNE fp32->bf16
  uint32_t x = __float_as_uint(f);
  x += 0x7fffu + ((x >> 16) & 1u);
  return (u16)(x >> 16);
}
__device__ __forceinline__ float bf2f(u16 u) {
  return __uint_as_float(((uint32_t)u) << 16);
}
__device__ __forceinline__ float f16bits(uint32_t bits) {  // low 16b as f16
  f16 h;
  u16 b = (u16)bits;
  __builtin_memcpy(&h, &b, 2);
  return (float)h;
}
__device__ __forceinline__ u16 h2bits(f16 h) {
  u16 b;
  __builtin_memcpy(&b, &h, 2);
  return b;
}
__device__ __forceinline__ uint8_t f2fp8(float f) {  // OCP e4m3 (fallback)
  __hip_fp8_e4m3 h(f);
  return (uint8_t)h.__x;
}
__device__ __forceinline__ float fp82f(uint8_t b) {
  __hip_fp8_e4m3 h;
  h.__x = (__hip_fp8_storage_t)b;
  return (float)h;
}
// Pack 4 f32 -> 4 fp8 e4m3 bytes (byte j = value j).
__device__ __forceinline__ uint32_t pk4_fp8(float a, float b, float c, float d) {
#if defined(__has_builtin) && __has_builtin(__builtin_amdgcn_cvt_pk_fp8_f32)
  int v = __builtin_amdgcn_cvt_pk_fp8_f32(a, b, 0, false);   // bytes 0,1
  v = __builtin_amdgcn_cvt_pk_fp8_f32(c, d, v, true);        // bytes 2,3
  return (uint32_t)v;
#else
  return (uint32_t)f2fp8(a) | ((uint32_t)f2fp8(b) << 8) |
         ((uint32_t)f2fp8(c) << 16) | ((uint32_t)f2fp8(d) << 24);
#endif
}
// Pack 2 f32 -> 2 f16 (RTZ) in one instruction.
__device__ __forceinline__ uint32_t pkrtz(float a, float b) {
  uint32_t d;
  asm("v_cvt_pkrtz_f16_f32 %0, %1, %2" : "=v"(d) : "v"(a), "v"(b));
  return d;
}
__device__ __forceinline__ uint32_t pk_max16(uint32_t a, uint32_t b) {
  uint32_t d;
  asm("v_pk_max_f16 %0, %1, %2" : "=v"(d) : "v"(a), "v"(b));
  return d;
}
__device__ __forceinline__ uint32_t pk_min16(uint32_t a, uint32_t b) {
  uint32_t d;
  asm("v_pk_min_f16 %0, %1, %2" : "=v"(d) : "v"(a), "v"(b));
  return d;
}

// async global->LDS, 16B per lane; lds base wave-uniform.
__device__ __forceinline__ void gload_lds16(const u16* g, u16* lds) {
  __builtin_amdgcn_global_load_lds(
      (const __attribute__((address_space(1))) uint32_t*)g,
      (__attribute__((address_space(3))) uint32_t*)lds,
      16, 0, 0);
}

// Insert v into descending-sorted N-element register array (fp32).
template <int N>
__device__ __forceinline__ void insN(float (&t)[N], float v) {
  #pragma unroll
  for (int j = 0; j < N; ++j) {
    float hi = fmaxf(t[j], v);
    v = fminf(t[j], v);
    t[j] = hi;
  }
}
// Packed variant: two independent sorted-desc f16 lists in lo/hi halves.
template <int N>
__device__ __forceinline__ void pinsN(uint32_t (&t)[N], uint32_t v) {
  #pragma unroll
  for (int j = 0; j < N; ++j) {
    uint32_t hi = pk_max16(t[j], v);
    v = pk_min16(t[j], v);
    t[j] = hi;
  }
}

// Fused: cast L (blocks [0,4096)), cast R ([4096,8192)), diag ([8192,12288)).
// diag dots the fp32 inputs directly (no dependency on the casts).
__global__ __launch_bounds__(256) void fused_pre(const float* __restrict__ L,
                                                 const float* __restrict__ R,
                                                 u16* __restrict__ Lb,
                                                 u16* __restrict__ Rb,
                                                 float* __restrict__ diag) {
  const int b = blockIdx.x;
  const int tid = threadIdx.x;
  if (b < 8192) {
    const float* src = (b < 4096) ? L : R;
    u16* dst = (b < 4096) ? Lb : Rb;
    int bb = (b < 4096) ? b : b - 4096;
    int i = (bb * 256 + tid) * 8;
    const float4* s4 = reinterpret_cast<const float4*>(src + i);
    float4 a = s4[0], c = s4[1];
    sh8 o;
    o[0] = (short)f2bf(a.x); o[1] = (short)f2bf(a.y);
    o[2] = (short)f2bf(a.z); o[3] = (short)f2bf(a.w);
    o[4] = (short)f2bf(c.x); o[5] = (short)f2bf(c.y);
    o[6] = (short)f2bf(c.z); o[7] = (short)f2bf(c.w);
    *reinterpret_cast<sh8*>(dst + i) = o;
  } else {
    int db = b - 8192;
    int r = db * 4 + (tid >> 6);
    int lane = tid & 63;
    const float4* la = reinterpret_cast<const float4*>(L + (size_t)r * DD + lane * 8);
    const float4* rb = reinterpret_cast<const float4*>(R + (size_t)r * DD + lane * 8);
    float4 a0 = la[0], a1 = la[1], b0 = rb[0], b1 = rb[1];
    float s = a0.x * b0.x + a0.y * b0.y + a0.z * b0.z + a0.w * b0.w +
              a1.x * b1.x + a1.y * b1.y + a1.z * b1.z + a1.w * b1.w;
    #pragma unroll
    for (int off = 32; off > 0; off >>= 1) s += __shfl_down(s, off);
    if (lane == 0) diag[r] = s;
  }
}

// Block-coordinate decode: 128 rowtiles (BM=128) x 64 coltiles (BN=256).
// xcd = blk&7 -> fixed 16-rowtile A-band per XCD; coltile sweeps slowly.
// 512 threads = 8 waves in a 2x4 (row x col) grid of 64x64 wave tiles.
#define DECODE_TILE(ct0)                                \
  const int xcd = blockIdx.x & 7;                       \
  const int idx = blockIdx.x >> 3;                      \
  const int rowtile = xcd * 16 + (idx & 15);            \
  const int coltile = (ct0) + (idx >> 4);               \
  const int rowbase = rowtile * BM;                     \
  const int colbase = coltile * BN;                     \
  const int tid = threadIdx.x;                          \
  const int w = tid >> 6;                               \
  const int lane = tid & 63;                            \
  const int quad = lane >> 4;                           \
  const int l16 = lane & 15;                            \
  const int wr = (w >> 2) * 64;                         \
  const int wc = (w & 3) * 64;                          \
  (void)xcd; (void)lane;

// ---- BK=32 3-buffer single-barrier prefetch K-loop, wave 64x64, 512t ----
// Buffer u16 offsets: A tiles (4096 u16) at {0,4096,8192}; B tiles (8192
// u16) at {12288,20480,28672}; 73728 B total (2 blocks/CU). STAGE(t+2) is
// issued BEFORE the MFMA cluster: its target buf[(t+2)%3] was last read
// during compute t-1, and every wave passed the top-of-t barrier after
// that. Per-wave vmcnt(3) before the barrier = own STAGE(t) loads landed.
#define GEMM_PRE()                                                              \
  const int rp0_ = tid >> 3, gp0_ = (tid & 7) ^ (rp0_ & 7);                     \
  const int grow0_ = rp0_ * 2 + (gp0_ >> 2), gcol0_ = (gp0_ & 3) * 8;           \
  const int gl1_ = tid + 512;                                                   \
  const int rp1_ = gl1_ >> 3, gp1_ = (gl1_ & 7) ^ (rp1_ & 7);                   \
  const int grow1_ = rp1_ * 2 + (gp1_ >> 2), gcol1_ = (gp1_ & 3) * 8;           \
  const u16* gA_  = A + (size_t)(rowbase + grow0_) * DD + gcol0_;               \
  const u16* gB0_ = B + (size_t)(colbase + grow0_) * DD + gcol0_;               \
  const u16* gB1_ = B + (size_t)(colbase + grow1_) * DD + gcol1_;               \
  const int gsel_ = ((((l16) & 1) << 2) + quad) ^ (l16 >> 1);                   \
  const int rdA_ = (wr / 2 + (l16 >> 1)) * 64 + gsel_ * 8;                      \
  const int rdB_ = (wc / 2 + (l16 >> 1)) * 64 + gsel_ * 8;

#define STAGE(t, dA, dB)                                                        \
  gload_lds16(gA_  + (t) * 32, (dA) + tid * 8);                                 \
  gload_lds16(gB0_ + (t) * 32, (dB) + tid * 8);                                 \
  gload_lds16(gB1_ + (t) * 32, (dB) + 4096 + tid * 8);

#define GEMM_K_LOOP(smembase)                                                   \
  f32x4 acc[4][4];                                                              \
  _Pragma("unroll")                                                             \
  for (int a_ = 0; a_ < 4; ++a_)                                                \
    _Pragma("unroll")                                                           \
    for (int b_ = 0; b_ < 4; ++b_) acc[a_][b_] = (f32x4){0.f, 0.f, 0.f, 0.f};   \
  {                                                                             \
    GEMM_PRE()                                                                  \
    u16* const bA_[3] = {(smembase), (smembase) + 4096, (smembase) + 8192};     \
    u16* const bB_[3] = {(smembase) + 12288, (smembase) + 20480,                \
                         (smembase) + 28672};                                   \
    STAGE(0, bA_[0], bB_[0])                                                    \
    STAGE(1, bA_[1], bB_[1])                                                    \
    _Pragma("unroll")                                                           \
    for (int t = 0; t < 16; ++t) {                                              \
      if (t < 15) { asm volatile("s_waitcnt vmcnt(3)" ::: "memory"); }          \
      else        { asm volatile("s_waitcnt vmcnt(0)" ::: "memory"); }          \
      __builtin_amdgcn_s_barrier();                                             \
      asm volatile("" ::: "memory");                                            \
      {                                                                         \
        const int cs_ = t % 3;                                                  \
        const u16* cA_ = bA_[cs_];                                              \
        const u16* cB_ = bB_[cs_];                                              \
        bf16x8 af[4], bfv[4];                                                   \
        _Pragma("unroll")                                                       \
        for (int f = 0; f < 4; ++f)                                             \
          af[f]  = *reinterpret_cast<const bf16x8*>(cA_ + rdA_ + f * 512);      \
        _Pragma("unroll")                                                       \
        for (int f = 0; f < 4; ++f)                                             \
          bfv[f] = *reinterpret_cast<const bf16x8*>(cB_ + rdB_ + f * 512);      \
        if (t + 2 < 16) {                                                       \
          const int ns_ = (t + 2) % 3;                                          \
          STAGE(t + 2, bA_[ns_], bB_[ns_])                                      \
        }                                                                       \
        __builtin_amdgcn_s_setprio(1);                                          \
        _Pragma("unroll")                                                       \
        for (int fr = 0; fr < 4; ++fr)                                          \
          _Pragma("unroll")                                                     \
          for (int fc = 0; fc < 4; ++fc)                                        \
            acc[fr][fc] = __builtin_amdgcn_mfma_f32_16x16x32_bf16(af[fr], bfv[fc], acc[fr][fc], 0, 0, 0); \
        __builtin_amdgcn_s_setprio(0);                                          \
      }                                                                         \
      asm volatile("" ::: "memory");                                            \
    }                                                                           \
  }

// Pass 1: G2 tile + row top-4 partials (RL) + col top-4 partials (LR).
// rowp[coltile][row][4] f16 (64 segs); colp[rowtile][col][4] f16 (128 segs).
// coltile < SC2 additionally dumps the tile as fp8 e4m3 to sim.
// Epilogue LDS view: [64 rowpairs][260 dwords], dword(rp,c) = f16 pair
// (row 2rp, row 2rp+1) of column c.
__global__ __launch_bounds__(512, 4) void gemm_topk(const u16* __restrict__ A,
                                                    const u16* __restrict__ B,
                                                    f16* __restrict__ rowp,
                                                    f16* __restrict__ colp,
                                                    uint8_t* __restrict__ sim,
                                                    int SC2) {
  __shared__ __align__(16) u16 smem[36864];  // 73728 B (3-buf; epi view 66560 B)
  DECODE_TILE(0)
  GEMM_K_LOOP(smem)

  __syncthreads();  // all waves done with K-loop LDS before epilogue reuse
  uint32_t* hC32 = reinterpret_cast<uint32_t*>(smem);
  // pair-packed fp16 dump: 32 b32 writes + 32 pkrtz per thread
  #pragma unroll
  for (int fr = 0; fr < 4; ++fr) {
    const int rpb = (wr + 16 * fr) / 2 + quad * 2;
    #pragma unroll
    for (int fc = 0; fc < 4; ++fc) {
      const int c = wc + 16 * fc + l16;
      hC32[rpb * PPW + c]       = pkrtz(acc[fr][fc][0], acc[fr][fc][1]);
      hC32[(rpb + 1) * PPW + c] = pkrtz(acc[fr][fc][2], acc[fr][fc][3]);
    }
  }
  __syncthreads();
  // global fp8 sim store: thread (rp0=tid>>6, cb=tid&63); 8 itw iterations
  if (coltile < SC2) {
    const int SW = SC2 * BN;
    uint8_t* gs = sim + (size_t)rowbase * SW + (size_t)coltile * BN;
    const int rp0s = tid >> 6, cb = tid & 63;
    #pragma unroll
    for (int itw = 0; itw < 8; ++itw) {
      const int rp = rp0s + itw * 8;
      uint4 v = *reinterpret_cast<const uint4*>(&hC32[rp * PPW + cb * 4]);
      uint32_t d0 = v.x, d1 = v.y, d2 = v.z, d3 = v.w;
      uint32_t r0 = pk4_fp8(f16bits(d0), f16bits(d1), f16bits(d2), f16bits(d3));
      uint32_t r1 = pk4_fp8(f16bits(d0 >> 16), f16bits(d1 >> 16),
                            f16bits(d2 >> 16), f16bits(d3 >> 16));
      *reinterpret_cast<uint32_t*>(gs + (size_t)(2 * rp) * SW + cb * 4) = r0;
      *reinterpret_cast<uint32_t*>(gs + (size_t)(2 * rp + 1) * SW + cb * 4) = r1;
    }
  }
  // ---- packed row scan: thread owns rowpair rsp = tid>>3, col-eighth
  // ce = tid&7 (32 cols). Each dword: lo = even row, hi = odd row.
  uint32_t trow[KT];
  #pragma unroll
  for (int j = 0; j < KT; ++j) trow[j] = 0xFBFFFBFFu;  // -65504 packed
  const int rsp = tid >> 3, ce = tid & 7;
  #pragma unroll
  for (int k = 0; k < 8; ++k) {
    uint4 ch = *reinterpret_cast<const uint4*>(&hC32[rsp * PPW + ce * 32 + k * 4]);
    pinsN<KT>(trow, ch.x);
    pinsN<KT>(trow, ch.y);
    pinsN<KT>(trow, ch.z);
    pinsN<KT>(trow, ch.w);
  }
  // ---- packed col scan: thread owns col cc = tid&255, rowpair-half
  // rph = tid>>8 (32 rowpairs). lo = even rows, hi = odd rows of col cc.
  uint32_t tcol[KT];
  #pragma unroll
  for (int j = 0; j < KT; ++j) tcol[j] = 0xFBFFFBFFu;
  const int cc = tid & 255, rph = tid >> 8;
  #pragma unroll 8
  for (int i = 0; i < 32; ++i) {
    uint32_t v = hC32[(rph * 32 + i) * PPW + cc];
    pinsN<KT>(tcol, v);
  }
  __syncthreads();
  // list regions (overlap pair view; all reads done at the barrier above)
  uint32_t* sRl = hC32;                   // [64 rp][8 ce][KT] = 2048 dw
  uint32_t* sCl = hC32 + 64 * 8 * KT;     // [256 c][2 rph][KT] = 2048 dw
  #pragma unroll
  for (int j = 0; j < KT; ++j) sRl[(rsp * 8 + ce) * KT + j] = trow[j];
  #pragma unroll
  for (int j = 0; j < KT; ++j) sCl[(cc * 2 + rph) * KT + j] = tcol[j];
  __syncthreads();
  if (tid < 256) {
    // col merge (col c = tid): 2 rph x 2 row-parities = 4 sorted streams
    float best[KT];
    #pragma unroll
    for (int j = 0; j < KT; ++j) best[j] = NEG_INF;
    for (int rh = 0; rh < 2; ++rh)
      for (int par = 0; par < 2; ++par)
        for (int j = 0; j < KT; ++j) {
          uint32_t u = sCl[(tid * 2 + rh) * KT + j];
          float v = f16bits(par ? (u >> 16) : u);
          if (v > best[KT - 1]) insN<KT>(best, v);
          else break;  // stream sorted desc
        }
    f16* o = colp + ((size_t)rowtile * NN + colbase + tid) * KT;
    uint2 ov;
    ov.x = h2bits((f16)best[0]) | ((uint32_t)h2bits((f16)best[1]) << 16);
    ov.y = h2bits((f16)best[2]) | ((uint32_t)h2bits((f16)best[3]) << 16);
    *reinterpret_cast<uint2*>(o) = ov;
  } else if (tid < 384) {
    // row merge (row r = tid-256): 8 ce streams, parity-selected half
    const int r = tid - 256;
    const int rp = r >> 1, par = r & 1;
    float best[KT];
    #pragma unroll
    for (int j = 0; j < KT; ++j) best[j] = NEG_INF;
    for (int h = 0; h < 8; ++h)
      for (int j = 0; j < KT; ++j) {
        uint32_t u = sRl[(rp * 8 + h) * KT + j];
        float v = f16bits(par ? (u >> 16) : u);
        if (v > best[KT - 1]) insN<KT>(best, v);
        else break;
      }
    f16* o = rowp + ((size_t)coltile * NN + rowbase + r) * KT;
    uint2 ov;
    ov.x = h2bits((f16)best[0]) | ((uint32_t)h2bits((f16)best[1]) << 16);
    ov.y = h2bits((f16)best[2]) | ((uint32_t)h2bits((f16)best[3]) << 16);
    *reinterpret_cast<uint2*>(o) = ov;
  }
}

// Fused pass 2: blocks [0, NR*128) recompute GEMM+rank for coltile >= SC2;
// blocks [NR*128, NR*128+2048) stream-scan the fp8 sim (8 rows per block).
// Independent work items -> concurrent execution overlaps compute & HBM.
__global__ __launch_bounds__(512, 4) void fused_post(const u16* __restrict__ A,
                                                     const u16* __restrict__ B,
                                                     const float* __restrict__ p,
                                                     const float* __restrict__ thr,
                                                     const uint8_t* __restrict__ sim,
                                                     int SC2, int NR,
                                                     int* __restrict__ cnt_out,
                                                     float* __restrict__ mx_out,
                                                     int* __restrict__ cnt_s,
                                                     float* __restrict__ mx_s) {
  __shared__ __align__(16) u16 smem[36864];  // 73728 B
  if ((int)blockIdx.x < NR * 128) {
    // ---------------- rank branch ----------------
    DECODE_TILE(SC2)
    GEMM_K_LOOP(smem)

    float thrv[16];
    #pragma unroll
    for (int i = 0; i < 16; ++i)
      thrv[i] = thr[rowbase + wr + 16 * (i >> 2) + quad * 4 + (i & 3)];
    float pv[4];
    #pragma unroll
    for (int fc = 0; fc < 4; ++fc) pv[fc] = p[colbase + wc + 16 * fc + l16];

    int cnt[16];
    float mx[16];
    #pragma unroll
    for (int i = 0; i < 16; ++i) { cnt[i] = 0; mx[i] = NEG_INF; }
    #pragma unroll
    for (int fc = 0; fc < 4; ++fc)
      #pragma unroll
      for (int fr = 0; fr < 4; ++fr)
        #pragma unroll
        for (int reg = 0; reg < 4; ++reg) {
          float t2 = 2.f * acc[fr][fc][reg] - pv[fc];
          int idx2 = fr * 4 + reg;
          cnt[idx2] += (t2 > thrv[idx2]) ? 1 : 0;
          mx[idx2] = fmaxf(mx[idx2], t2);
        }

    __syncthreads();  // all waves done with K-loop LDS before buffer reuse
    float* sMx = reinterpret_cast<float*>(smem);        // [8][64]
    int*   sCn = reinterpret_cast<int*>(smem) + 512;    // [8][64]
    #pragma unroll
    for (int idx2 = 0; idx2 < 16; ++idx2) {
      int c = cnt[idx2];
      float m = mx[idx2];
      #pragma unroll
      for (int off = 1; off < 16; off <<= 1) {
        c += __shfl_xor(c, off);
        m = fmaxf(m, __shfl_xor(m, off));
      }
      if (l16 == 0) {
        int rloc = 16 * (idx2 >> 2) + quad * 4 + (idx2 & 3);
        sMx[w * 64 + rloc] = m;
        sCn[w * 64 + rloc] = c;
      }
    }
    __syncthreads();
    if (tid < 128) {
      int g0 = (tid >> 6) * 4, rloc = tid & 63;
      int c = 0;
      float m = NEG_INF;
      #pragma unroll
      for (int k = 0; k < 4; ++k) {
        c += sCn[(g0 + k) * 64 + rloc];
        m = fmaxf(m, sMx[(g0 + k) * 64 + rloc]);
      }
      cnt_out[(size_t)coltile * NN + rowbase + tid] = c;
      mx_out[(size_t)coltile * NN + rowbase + tid] = m;
    }
  } else {
    // ---------------- scan branch (512 thr, 8 rows/block) ----------------
    const int tid = threadIdx.x;
    const int sblk = blockIdx.x - NR * 128;
    const int row0 = sblk * 8;
    const int SW = SC2 * BN;
    float t[8];
    #pragma unroll
    for (int r = 0; r < 8; ++r) t[r] = thr[row0 + r];
    int cnt[8];
    float m[8];
    #pragma unroll
    for (int r = 0; r < 8; ++r) { cnt[r] = 0; m[r] = NEG_INF; }
    for (int c0 = tid * 16; c0 < SW; c0 += 8192) {
      float pv[16];
      {
        const float4* p4 = reinterpret_cast<const float4*>(p + c0);
        *reinterpret_cast<float4*>(&pv[0])  = p4[0];
        *reinterpret_cast<float4*>(&pv[4])  = p4[1];
        *reinterpret_cast<float4*>(&pv[8])  = p4[2];
        *reinterpret_cast<float4*>(&pv[12]) = p4[3];
      }
      #pragma unroll
      for (int r = 0; r < 8; ++r) {
        uint4 v = *reinterpret_cast<const uint4*>(sim + (size_t)(row0 + r) * SW + c0);
        uint32_t wds[4] = {v.x, v.y, v.z, v.w};
        #pragma unroll
        for (int j = 0; j < 16; ++j) {
          float sv = fp82f((uint8_t)(wds[j >> 2] >> ((j & 3) * 8)));
          float t2 = 2.f * sv - pv[j];
          cnt[r] += (t2 > t[r]) ? 1 : 0;
          m[r] = fmaxf(m[r], t2);
        }
      }
    }
    float* sM = reinterpret_cast<float*>(smem);        // [8 rows][8 waves]
    int*   sC = reinterpret_cast<int*>(smem) + 64;     // [8 rows][8 waves]
    const int lane = tid & 63, wv = tid >> 6;
    #pragma unroll
    for (int r = 0; r < 8; ++r) {
      int c = cnt[r];
      float mm = m[r];
      #pragma unroll
      for (int off = 32; off > 0; off >>= 1) {
        c += __shfl_down(c, off);
        mm = fmaxf(mm, __shfl_down(mm, off));
      }
      if (lane == 0) { sC[r * 8 + wv] = c; sM[r * 8 + wv] = mm; }
    }
    __syncthreads();
    if (tid < 8) {
      int c = 0;
      float mm = NEG_INF;
      #pragma unroll
      for (int k = 0; k < 8; ++k) {
        c += sC[tid * 8 + k];
        mm = fmaxf(mm, sM[tid * 8 + k]);
      }
      cnt_s[row0 + tid] = c;
      mx_s[row0 + tid] = mm;
    }
  }
}

// p[l] = mean(top10 of rowp[*][l]) + mean(top10 of colp[*][l]); thr = 2*diag - p.
// 8 threads per entity (segment subsets) + LDS merge; uint2 per segment.
__global__ __launch_bounds__(256) void p_kernel(const f16* __restrict__ rowp,
                                                const f16* __restrict__ colp,
                                                const float* __restrict__ diag,
                                                float* __restrict__ pout,
                                                float* __restrict__ throut) {
  __shared__ float sB1[32][8][10];
  __shared__ float sB2[32][8][10];
  const int tid = threadIdx.x;
  const int lent = tid >> 3, part = tid & 7;
  const int l = blockIdx.x * 32 + lent;
  float b1[10], b2[10];
  #pragma unroll
  for (int j = 0; j < 10; ++j) { b1[j] = NEG_INF; b2[j] = NEG_INF; }
  for (int s = part * 8; s < part * 8 + 8; ++s) {
    uint2 u2 = *reinterpret_cast<const uint2*>(rowp + ((size_t)s * NN + l) * KT);
    uint32_t ud[2] = {u2.x, u2.y};
    #pragma unroll
    for (int d = 0; d < 2; ++d) {
      uint32_t u = ud[d];
      float v0 = f16bits(u), v1 = f16bits(u >> 16);
      if (v0 > b1[9]) insN<10>(b1, v0); else break;
      if (v1 > b1[9]) insN<10>(b1, v1); else break;
    }
  }
  for (int s = part * 16; s < part * 16 + 16; ++s) {
    uint2 u2 = *reinterpret_cast<const uint2*>(colp + ((size_t)s * NN + l) * KT);
    uint32_t ud[2] = {u2.x, u2.y};
    #pragma unroll
    for (int d = 0; d < 2; ++d) {
      uint32_t u = ud[d];
      float v0 = f16bits(u), v1 = f16bits(u >> 16);
      if (v0 > b2[9]) insN<10>(b2, v0); else break;
      if (v1 > b2[9]) insN<10>(b2, v1); else break;
    }
  }
  #pragma unroll
  for (int j = 0; j < 10; ++j) { sB1[lent][part][j] = b1[j]; sB2[lent][part][j] = b2[j]; }
  __syncthreads();
  if (tid < 32) {
    const int l2 = blockIdx.x * 32 + tid;
    float m1[10], m2[10];
    #pragma unroll
    for (int j = 0; j < 10; ++j) { m1[j] = NEG_INF; m2[j] = NEG_INF; }
    for (int pa = 0; pa < 8; ++pa) {
      for (int j = 0; j < 10; ++j) {
        float v = sB1[tid][pa][j];
        if (v > m1[9]) insN<10>(m1, v); else break;  // partial sorted desc
      }
      for (int j = 0; j < 10; ++j) {
        float v = sB2[tid][pa][j];
        if (v > m2[9]) insN<10>(m2, v); else break;
      }
    }
    float s1 = 0.f, s2 = 0.f;
    #pragma unroll
    for (int j = 0; j < 10; ++j) { s1 += m1[j]; s2 += m2[j]; }
    float pv = (s1 + s2) * 0.1f;
    pout[l2] = pv;
    throut[l2] = 2.f * diag[l2] - pv;
  }
}

// Combine scan partial (stored cols) + per-coltile partials (recomputed cols).
// cnt/mx are [coltile][row] -> coalesced reads.
__global__ __launch_bounds__(256) void final_kernel(const int* __restrict__ cnt,
                                                    const float* __restrict__ mx,
                                                    const int* __restrict__ cnt_s,
                                                    const float* __restrict__ mx_s,
                                                    int sc2,
                                                    float* __restrict__ out) {
  int r = blockIdx.x * 256 + threadIdx.x;
  int c = 0;
  float m = NEG_INF;
  if (sc2 > 0) { c = cnt_s[r]; m = mx_s[r]; }
  for (int s = sc2; s < NCT2; ++s) {
    c += cnt[(size_t)s * NN + r];
    m = fmaxf(m, mx[(size_t)s * NN + r]);
  }
  out[r] = (float)c;   // rank of the diagonal element (count strictly greater)
  out[NN + r] = m;     // top-1 csls value
}

extern "C" void kernel_launch(void* const* d_in, const int* in_sizes, int n_in,
                              void* d_out, int out_size, void* d_ws, size_t ws_size,
                              hipStream_t stream) {
  const float* L = (const float*)d_in[0];
  const float* R = (const float*)d_in[1];
  char* ws = (char*)d_ws;

  const size_t PART_ROW = (size_t)NCT2 * NN * KT * 2;   // 8.39 MB
  const size_t PART_COL = (size_t)128 * NN * KT * 2;    // 16.78 MB
  const size_t TAILOFF = (32ull << 20) + PART_ROW + PART_COL;
  const size_t SIMOFF = TAILOFF + (320ull << 10);

  u16* Lb   = (u16*)ws;                                 // 16 MiB
  u16* Rb   = (u16*)(ws + (16ull << 20));               // 16 MiB
  f16* rowp = (f16*)(ws + (32ull << 20));               // [64 seg][NN][KT]
  f16* colp = (f16*)(ws + (32ull << 20) + PART_ROW);    // [128 seg][NN][KT]
  char* tail = ws + TAILOFF;
  float* diag   = (float*)tail;
  float* pbuf   = (float*)(tail + (64ull << 10));
  float* thrbuf = (float*)(tail + (128ull << 10));
  int*   cnt_s  = (int*)(tail + (192ull << 10));
  float* mx_s   = (float*)(tail + (256ull << 10));
  uint8_t* sim  = (uint8_t*)(ws + SIMOFF);
  // cnt/mx alias partial regions (fully consumed by p_kernel first)
  int*   cntp = (int*)rowp;                             // 4.2 MB
  float* mxp  = (float*)colp;                           // 4.2 MB

  // Stored 256-wide column-tiles in fp8: 4.19 MB each.
  int SC2 = 0;
  if (ws_size > SIMOFF) {
    size_t sc = (ws_size - SIMOFF) / ((size_t)NN * BN * 1);
    if (sc > 64) sc = 64;
    SC2 = (int)sc;
  }
  const int NR = NCT2 - SC2;

  // 1) casts + diag (diag from fp32 inputs, independent of casts)
  fused_pre<<<12288, 256, 0, stream>>>(L, R, Lb, Rb, diag);
  // 2) pass 1 over G2 = R*L^T: top-4 partials + fp8 sim store for coltile < SC2
  gemm_topk<<<(NN / BM) * NCT2, 512, 0, stream>>>(Rb, Lb, rowp, colp, sim, SC2);
  // 3) merge partials -> p, thr
  p_kernel<<<NN / 32, 256, 0, stream>>>(rowp, colp, diag, pbuf, thrbuf);
  // 4) fused pass 2: rank (NR coltiles) || scan (stored coltiles)
  {
    int grid = NR * 128 + (SC2 > 0 ? (NN / 8) : 0);
    if (grid > 0)
      fused_post<<<grid, 512, 0, stream>>>(Rb, Lb, pbuf, thrbuf, sim, SC2, NR,
                                           cntp, mxp, cnt_s, mx_s);
  }
  // 5) combine -> outputs
  final_kernel<<<NN / 256, 256, 0, stream>>>(cntp, mxp, cnt_s, mx_s, SC2,
                                             (float*)d_out);
}